// Round 1
// baseline (373.424 us; speedup 1.0000x reference)
//
#include <hip/hip_runtime.h>

// TaylorExp: x [B,H,S,16] fp32 -> out [B,H,S,273] fp32
//   out[..., 0]      = 1.0
//   out[..., 1..16]  = x / 2              (RRD = sqrt(sqrt(16)) = 2)
//   out[..., 17+i*16+j] = x_i * x_j / (sqrt(2)*4)
//
// Write-BW-bound: 286 MB out vs 16 MB in. Flat-index output, one float4
// store per thread, 1 int-div (magic mul) per thread.

#define C_LIN  0.5f
#define C_QUAD 0.17677669529663687f   // 1/(4*sqrt(2))

__global__ __launch_bounds__(256) void taylor_exp_kernel(
    const float* __restrict__ x, float* __restrict__ out, int n4) {
    const int stride = gridDim.x * blockDim.x;
    for (int t = blockIdx.x * blockDim.x + threadIdx.x; t < n4; t += stride) {
        unsigned base = (unsigned)t * 4u;
        unsigned row  = base / 273u;          // compiler emits magic-mul
        unsigned k    = base - row * 273u;
        const float* xr = x + (size_t)row * 16u;
        float4 o;
        float* op = reinterpret_cast<float*>(&o);
        #pragma unroll
        for (int e = 0; e < 4; ++e) {
            if (k >= 273u) { k -= 273u; xr += 16; }
            float v;
            if (k == 0u) {
                v = 1.0f;
            } else if (k <= 16u) {
                v = xr[k - 1u] * C_LIN;
            } else {
                unsigned q = k - 17u;
                v = xr[q >> 4] * xr[q & 15u] * C_QUAD;
            }
            op[e] = v;
            ++k;
        }
        reinterpret_cast<float4*>(out)[t] = o;
    }
}

extern "C" void kernel_launch(void* const* d_in, const int* in_sizes, int n_in,
                              void* d_out, int out_size, void* d_ws, size_t ws_size,
                              hipStream_t stream) {
    const float* x = (const float*)d_in[0];
    float* out = (float*)d_out;
    int n4 = out_size / 4;                       // 71,565,312 / 4 = 17,891,328
    int blocks = 2048;                           // 8 blocks/CU * 256 CUs
    taylor_exp_kernel<<<dim3(blocks), dim3(256), 0, stream>>>(x, out, n4);
}

// Round 2
// 302.018 us; speedup vs baseline: 1.2364x; 1.2364x over previous
//
#include <hip/hip_runtime.h>

// TaylorExp: x [B,H,S,16] fp32 -> out [B,H,S,273] fp32
//   out[..., 0]         = 1.0
//   out[..., 1..16]     = x * 0.5                  (RRD = 2)
//   out[..., 17+16i+j]  = x_i * x_j * 1/(4*sqrt(2))
//
// R2 theory: R1's per-lane global gathers (8 dword/iter) serialized the VMEM
// pipe. Stage 64 rows (4 KB) in LDS per block; gathers become ds_read_b32
// (broadcast / <=2-way conflict = free). Stores stay 1x float4, coalesced.

#define C_LIN  0.5f
#define C_QUAD 0.17677669529663687f   // 1/(4*sqrt(2))

#define ROWS_PER_TILE 64
#define TILE_F4       (ROWS_PER_TILE * 273 / 4)   // 4368 float4 per tile
#define TILE_IN_F4    (ROWS_PER_TILE * 16 / 4)    // 256 float4 of input

__global__ __launch_bounds__(256) void taylor_exp_kernel(
    const float* __restrict__ x, float* __restrict__ out, int ntiles) {
    __shared__ float xs[ROWS_PER_TILE * 16];      // 4 KB
    const int tid = threadIdx.x;

    for (int tile = blockIdx.x; tile < ntiles; tile += gridDim.x) {
        // coalesced stage: 256 threads x float4 = 4 KB = 64 rows
        reinterpret_cast<float4*>(xs)[tid] =
            reinterpret_cast<const float4*>(x)[(size_t)tile * TILE_IN_F4 + tid];
        __syncthreads();

        float4* outbase = reinterpret_cast<float4*>(out) + (size_t)tile * TILE_F4;
        for (int t = tid; t < TILE_F4; t += 256) {
            unsigned e   = (unsigned)t * 4u;          // elem index in tile, < 17472
            unsigned row = e / 273u;                  // magic-mul
            unsigned k   = e - row * 273u;
            const float* xr = xs + row * 16u;
            float4 o;
            float* op = reinterpret_cast<float*>(&o);
            #pragma unroll
            for (int i = 0; i < 4; ++i) {
                if (k >= 273u) { k -= 273u; xr += 16; }
                float v;
                if (k == 0u) {
                    v = 1.0f;
                } else if (k <= 16u) {
                    v = xr[k - 1u] * C_LIN;
                } else {
                    unsigned q = k - 17u;
                    v = xr[q >> 4] * xr[q & 15u] * C_QUAD;
                }
                op[i] = v;
                ++k;
            }
            outbase[t] = o;
        }
        __syncthreads();
    }
}

extern "C" void kernel_launch(void* const* d_in, const int* in_sizes, int n_in,
                              void* d_out, int out_size, void* d_ws, size_t ws_size,
                              hipStream_t stream) {
    const float* x = (const float*)d_in[0];
    float* out = (float*)d_out;
    int nrows  = in_sizes[0] / 16;            // 262144
    int ntiles = nrows / ROWS_PER_TILE;       // 4096 (divides exactly)
    int blocks = ntiles < 4096 ? ntiles : 4096;
    taylor_exp_kernel<<<dim3(blocks), dim3(256), 0, stream>>>(x, out, ntiles);
}

// Round 5
// 298.569 us; speedup vs baseline: 1.2507x; 1.0116x over previous
//
#include <hip/hip_runtime.h>

// TaylorExp: x [B,H,S,16] fp32 -> out [B,H,S,273] fp32 (rows of 273):
//   out[0]        = 1.0
//   out[1..16]    = x * 0.5                    (RRD = 2 exactly)
//   out[17+16i+j] = x_i * x_j * (1/(4*sqrt(2)))
//
// R3 (2nd resubmit after broker timeouts): wave-per-row scheme. Lane l owns
// elements k = 17 + 64p + l (p=0..3) plus head k=l (l<17). j = l&15 fixed
// per lane (1 ds_read/row), i = 4p + (l>>4) broadcast (4 ds_reads/row).
// All stores are coalesced store_dword with immediate offsets off one base
// address. No div, no per-element branching -> issue-bound cost drops ~12x
// vs R2; kernel becomes HBM-write-bound (~286 MB -> ~45-70 us).

#define C_QUAD 0.17677669529663687f   // 1/(4*sqrt(2))
#define ROWS_PER_BLOCK 128            // 4 waves x 32 rows, 8 KB LDS

__global__ __launch_bounds__(256) void taylor_exp_kernel(
    const float* __restrict__ x, float* __restrict__ out, int nrows) {
    __shared__ float xs[ROWS_PER_BLOCK * 16];   // 8 KB
    const int tid  = threadIdx.x;
    const int lane = tid & 63;
    const int wave = tid >> 6;
    const size_t row0 = (size_t)blockIdx.x * ROWS_PER_BLOCK;

    // stage 128 rows (8 KB) coalesced: 256 threads x 2 float4
    {
        const float4* src = reinterpret_cast<const float4*>(x + row0 * 16);
        float4* dst = reinterpret_cast<float4*>(xs);
        dst[tid]       = src[tid];
        dst[tid + 256] = src[tid + 256];
    }
    __syncthreads();

    const int j   = lane & 15;        // fixed j-operand index per lane
    const int ihi = lane >> 4;        // 0..3
    const int jm1 = (lane - 1) & 15;  // head operand index (lane>=1)

    // each wave owns a contiguous 32-row chunk for write locality
    const int rbeg = wave * 32;
    #pragma unroll 4
    for (int r = 0; r < 32; ++r) {
        const int row = rbeg + r;
        const float* xr = xs + row * 16;
        const float xj = xr[j];
        const float xh = xr[jm1];
        float* orow = out + (row0 + row) * 273u;

        // head: k = lane for lane < 17
        float head = (lane == 0) ? 1.0f : xh * 0.5f;
        if (lane < 17) orow[lane] = head;

        // quad block: k = 17 + 64p + lane
        #pragma unroll
        for (int p = 0; p < 4; ++p) {
            const float xi = xr[4 * p + ihi];
            orow[17 + 64 * p + lane] = (xi * C_QUAD) * xj;
        }
    }
}

extern "C" void kernel_launch(void* const* d_in, const int* in_sizes, int n_in,
                              void* d_out, int out_size, void* d_ws, size_t ws_size,
                              hipStream_t stream) {
    const float* x = (const float*)d_in[0];
    float* out = (float*)d_out;
    int nrows  = in_sizes[0] / 16;               // 262144
    int blocks = nrows / ROWS_PER_BLOCK;         // 2048, exact
    taylor_exp_kernel<<<dim3(blocks), dim3(256), 0, stream>>>(x, out, nrows);
}